// Round 10
// baseline (1891.012 us; speedup 1.0000x reference)
//
#include <hip/hip_runtime.h>
#include <hip/hip_bf16.h>
#include <stdint.h>

#define N_TOK 8192
#define DIM   2048
#define FDIM  4096
#define NEXP  8

// ---- ws layout (bytes) ---- total EXACTLY 310,902,912 = round-1 proven floor
#define XB_OFF   0ull                        // bf16 x  [8192][2048]    33,554,432
#define HB_OFF   33554432ull                 // bf16 h  [17408][4096]  142,606,336
#define WB1_OFF  176160768ull                // bf16 w1/w2 half         67,108,864
#define WB3_OFF  243269632ull                // bf16 w3 half / f32 down-partials 67,108,864
#define META_OFF 310378496ull
#define CNT_OFF   (META_OFF)                 // int[8] (64B)
#define EBASE_OFF (META_OFF + 64ull)         // int[8] (64B)
#define ELIST_OFF (META_OFF + 128ull)        // int[8][8192]  262,144
#define EWTS_OFF  (ELIST_OFF + 262144ull)    // f32[8][8192]  262,144  -> end 310,902,912

typedef float f32x4 __attribute__((ext_vector_type(4)));
typedef short s16x8 __attribute__((ext_vector_type(8)));

__device__ __forceinline__ uint32_t pkbf(float a, float b) {
  uint32_t ua = __builtin_bit_cast(uint32_t, a) + 0x8000u;
  uint32_t ub = __builtin_bit_cast(uint32_t, b) + 0x8000u;
  return (ua >> 16) | (ub & 0xffff0000u);
}

__device__ __forceinline__ void gld16(const void* g, void* l) {
  __builtin_amdgcn_global_load_lds(
      (__attribute__((address_space(1))) void*)g,
      (__attribute__((address_space(3))) void*)l, 16, 0, 0);
}

__global__ void init_k(int* cnt) {
  if (threadIdx.x < NEXP) cnt[threadIdx.x] = 0;
}

__global__ void router_k(const float* __restrict__ x, const float* __restrict__ gw,
                         __hip_bfloat16* __restrict__ xb, int* __restrict__ cnt,
                         int* __restrict__ elist, float* __restrict__ ewts) {
  const int n = blockIdx.x;
  const int t = threadIdx.x;
  const float* xr = x + (size_t)n * DIM;
  const float4 v0 = *(const float4*)(xr + t * 8);
  const float4 v1 = *(const float4*)(xr + t * 8 + 4);
  uint4 u;
  u.x = pkbf(v0.x, v0.y); u.y = pkbf(v0.z, v0.w);
  u.z = pkbf(v1.x, v1.y); u.w = pkbf(v1.z, v1.w);
  *(uint4*)(xb + (size_t)n * DIM + t * 8) = u;

  float p[NEXP];
#pragma unroll
  for (int e = 0; e < NEXP; ++e) {
    const float* g = gw + e * DIM + t * 8;
    const float4 g0 = *(const float4*)g;
    const float4 g1 = *(const float4*)(g + 4);
    p[e] = v0.x * g0.x + v0.y * g0.y + v0.z * g0.z + v0.w * g0.w +
           v1.x * g1.x + v1.y * g1.y + v1.z * g1.z + v1.w * g1.w;
  }
#pragma unroll
  for (int off = 32; off >= 1; off >>= 1)
#pragma unroll
    for (int e = 0; e < NEXP; ++e) p[e] += __shfl_xor(p[e], off, 64);

  __shared__ float red[4][NEXP];
  const int lane = t & 63, wv = t >> 6;
  if (lane == 0) {
#pragma unroll
    for (int e = 0; e < NEXP; ++e) red[wv][e] = p[e];
  }
  __syncthreads();
  if (t == 0) {
    float l0 = -1e30f, l1 = -1e30f;
    int e0 = 0, e1 = 0;
#pragma unroll
    for (int e = 0; e < NEXP; ++e) {
      float v = red[0][e] + red[1][e] + red[2][e] + red[3][e];
      if (v > l0) { l1 = l0; e1 = e0; l0 = v; e0 = e; }
      else if (v > l1) { l1 = v; e1 = e; }
    }
    const float ed = expf(l1 - l0);
    const float inv = 1.f / (1.f + ed);
    int s0 = atomicAdd(cnt + e0, 1);
    elist[e0 * N_TOK + s0] = n;
    ewts[e0 * N_TOK + s0] = inv;
    int s1 = atomicAdd(cnt + e1, 1);
    elist[e1 * N_TOK + s1] = (int)((uint32_t)n | 0x80000000u);
    ewts[e1 * N_TOK + s1] = ed * inv;
  }
}

__global__ void scan_k(const int* __restrict__ cnt, int* __restrict__ ebase) {
  if (threadIdx.x == 0 && blockIdx.x == 0) {
    int b = 0;
    for (int e = 0; e < NEXP; ++e) { ebase[e] = b; b += (cnt[e] + 127) & ~127; }
  }
}

// convert rows [r0, r0+nrh) of each expert's [rtot][kd] fp32 matrix -> bf16 [e][nrh][kd]
__global__ void convW_k(const float* __restrict__ src, __hip_bfloat16* __restrict__ dst,
                        int r0, int nrh, int rtot, int kd) {
  const int cpr = kd / 8;
  const int total = NEXP * nrh * cpr;
  for (int i = blockIdx.x * blockDim.x + threadIdx.x; i < total;
       i += gridDim.x * blockDim.x) {
    const int e = i / (nrh * cpr);
    const int rem = i - e * nrh * cpr;
    const int lr = rem / cpr;
    const int c = rem - lr * cpr;
    const float* s = src + ((size_t)e * rtot + r0 + lr) * (size_t)kd + c * 8;
    const float4 a = *(const float4*)s;
    const float4 b = *(const float4*)(s + 4);
    uint4 u;
    u.x = pkbf(a.x, a.y); u.y = pkbf(a.z, a.w);
    u.z = pkbf(b.x, b.y); u.w = pkbf(b.z, b.w);
    *(uint4*)(dst + ((size_t)e * nrh + lr) * (size_t)kd + c * 8) = u;
  }
}

// out[tok][noff + c] = part[slot0] + part[slot1] for one 1024-col D-half
__global__ void combine_k(const float* __restrict__ part, float* __restrict__ out,
                          int noff) {
  const size_t i4 = (size_t)blockIdx.x * 256 + threadIdx.x;   // 2,097,152 total
  const int tok = (int)(i4 >> 8);
  const int c = (int)(i4 & 255) * 4;
  const float4 a = *(const float4*)(part + ((size_t)tok) * 1024 + c);
  const float4 b = *(const float4*)(part + ((size_t)N_TOK + tok) * 1024 + c);
  float4 o;
  o.x = a.x + b.x; o.y = a.y + b.y; o.z = a.z + b.z; o.w = a.w + b.w;
  *(float4*)(out + (size_t)tok * DIM + noff + c) = o;
}

// ============================================================================
// Fused gate+up grouped GEMM (round-9 structure, now 3 blocks/CU): per 128x128
// tile, h = silu(x@w1h^T) * (x@w3h^T) over one N-half. BK=32, 4 waves, 2-stage
// LDS dbuf, all operands bf16 via global_load_lds w=16, plain 2-barrier K-loop.
// LDS 48KB: A@0, B1@16384, B3@32768 (2x8KB each) -> 3 blocks/CU.
// Swizzle (both sides): row r slot s holds src granule s^((r>>1)&3).
// ============================================================================
__global__ __launch_bounds__(256, 3) void moe_up_k(
    const __hip_bfloat16* __restrict__ xb, const __hip_bfloat16* __restrict__ w1b,
    const __hip_bfloat16* __restrict__ w3b, __hip_bfloat16* __restrict__ hb,
    const int* __restrict__ cnt, const int* __restrict__ ebase,
    const int* __restrict__ elist, int noff) {
  const int e = blockIdx.z;
  const int count = cnt[e];
  const int mt = blockIdx.y;
  if (mt * 128 >= count) return;
  const int bn0 = blockIdx.x * 128;          // col base within half
  const int ncol0 = noff + bn0;              // global F col base

  __shared__ char lds[49152];
  const int t = threadIdx.x;
  const int lane = t & 63, wv = t >> 6;
  const int wr = wv >> 1, wc = wv & 1;
  const int* lst = elist + e * N_TOK;
  const size_t hrow0 = (size_t)ebase[e] + (size_t)mt * 128;

  const int r0 = t >> 2;
  const int ks = (t & 3) ^ ((r0 >> 1) & 3);   // pre-swizzled source granule
  size_t sA[2], sB1[2];
  int ldsO[2];
#pragma unroll
  for (int i = 0; i < 2; ++i) {
    const int r = r0 + i * 64;
    int idx = mt * 128 + r;
    if (idx >= count) idx = 0;                 // clamp pad rows
    const size_t tok = (size_t)(lst[idx] & 0x7fffffff);
    sA[i] = tok * DIM + ks * 8;
    sB1[i] = ((size_t)e * 2048 + bn0 + r) * DIM + ks * 8;
    ldsO[i] = i * 4096 + wv * 1024;            // + lane*16 applied by HW
  }

  const int fr = lane & 15;
  const int swzc = ((lane >> 4) ^ ((fr >> 1) & 3)) << 4;
  const int aoff = (wr * 64 + fr) * 64 + swzc;
  const int boff = (wc * 64 + fr) * 64 + swzc;

  f32x4 accG[4][4], accU[4][4];
#pragma unroll
  for (int mi = 0; mi < 4; ++mi)
#pragma unroll
    for (int ni = 0; ni < 4; ++ni) {
      accG[mi][ni] = {0.f, 0.f, 0.f, 0.f};
      accU[mi][ni] = {0.f, 0.f, 0.f, 0.f};
    }

  auto stage = [&](int k0, int b) {
#pragma unroll
    for (int i = 0; i < 2; ++i)
      gld16(xb + sA[i] + k0, lds + b * 8192 + ldsO[i]);
#pragma unroll
    for (int i = 0; i < 2; ++i)
      gld16(w1b + sB1[i] + k0, lds + 16384 + b * 8192 + ldsO[i]);
#pragma unroll
    for (int i = 0; i < 2; ++i)
      gld16(w3b + sB1[i] + k0, lds + 32768 + b * 8192 + ldsO[i]);
  };

  stage(0, 0);
  __syncthreads();

  int b = 0;
  for (int kt = 0; kt < DIM / 32; ++kt) {
    const int nk = (kt + 1) * 32;
    if (nk < DIM) stage(nk, b ^ 1);
    s16x8 af[4], b1f[4], b3f[4];
#pragma unroll
    for (int mi = 0; mi < 4; ++mi)
      af[mi] = *(const s16x8*)(lds + b * 8192 + aoff + mi * 1024);
#pragma unroll
    for (int ni = 0; ni < 4; ++ni) {
      b1f[ni] = *(const s16x8*)(lds + 16384 + b * 8192 + boff + ni * 1024);
      b3f[ni] = *(const s16x8*)(lds + 32768 + b * 8192 + boff + ni * 1024);
    }
#pragma unroll
    for (int mi = 0; mi < 4; ++mi)
#pragma unroll
      for (int ni = 0; ni < 4; ++ni) {
        accG[mi][ni] = __builtin_amdgcn_mfma_f32_16x16x32_bf16(
            af[mi], b1f[ni], accG[mi][ni], 0, 0, 0);
        accU[mi][ni] = __builtin_amdgcn_mfma_f32_16x16x32_bf16(
            af[mi], b3f[ni], accU[mi][ni], 0, 0, 0);
      }
    __syncthreads();
    b ^= 1;
  }

  const int erow = (lane >> 4) * 4;
  const int ecol = lane & 15;
#pragma unroll
  for (int mi = 0; mi < 4; ++mi)
#pragma unroll
    for (int ni = 0; ni < 4; ++ni) {
      const size_t cb = ncol0 + wc * 64 + ni * 16 + ecol;
#pragma unroll
      for (int j = 0; j < 4; ++j) {
        const size_t r = hrow0 + wr * 64 + mi * 16 + erow + j;
        const float g = accG[mi][ni][j];
        const float uu = accU[mi][ni][j];
        const float h = g / (1.f + __expf(-g)) * uu;
        hb[r * FDIM + cb] = __float2bfloat16(h);
      }
    }
}

// ============================================================================
// Down grouped GEMM over one D-half: part[slot][tok][0..1023] = we*(h@w2h^T).
// Each (slot,tok,col) written exactly once -> no atomics, deterministic.
// LDS 32KB -> 3+ blocks/CU at launch_bounds(256,3).
// ============================================================================
__global__ __launch_bounds__(256, 3) void moe_down_k(
    const __hip_bfloat16* __restrict__ hb, const __hip_bfloat16* __restrict__ w2b,
    float* __restrict__ part, const int* __restrict__ cnt,
    const int* __restrict__ ebase, const int* __restrict__ elist,
    const float* __restrict__ ewts) {
  const int e = blockIdx.z;
  const int count = cnt[e];
  const int mt = blockIdx.y;
  if (mt * 128 >= count) return;
  const int bn0 = blockIdx.x * 128;          // col base within D-half (0..1023)

  __shared__ char lds[32768];
  const int t = threadIdx.x;
  const int lane = t & 63, wv = t >> 6;
  const int wr = wv >> 1, wc = wv & 1;
  const int* lst = elist + e * N_TOK;
  const size_t hrow0 = (size_t)ebase[e] + (size_t)mt * 128;

  const int r0 = t >> 2;
  const int ks = (t & 3) ^ ((r0 >> 1) & 3);
  size_t sA[2], sB[2];
  int ldsO[2];
#pragma unroll
  for (int i = 0; i < 2; ++i) {
    const int r = r0 + i * 64;
    sA[i] = (hrow0 + r) * (size_t)FDIM + ks * 8;
    sB[i] = ((size_t)e * 1024 + bn0 + r) * (size_t)FDIM + ks * 8;
    ldsO[i] = i * 4096 + wv * 1024;
  }

  const int fr = lane & 15;
  const int swzc = ((lane >> 4) ^ ((fr >> 1) & 3)) << 4;
  const int aoff = (wr * 64 + fr) * 64 + swzc;
  const int boff = 16384 + (wc * 64 + fr) * 64 + swzc;

  f32x4 acc[4][4];
#pragma unroll
  for (int mi = 0; mi < 4; ++mi)
#pragma unroll
    for (int ni = 0; ni < 4; ++ni) acc[mi][ni] = {0.f, 0.f, 0.f, 0.f};

  auto stage = [&](int k0, int b) {
#pragma unroll
    for (int i = 0; i < 2; ++i)
      gld16(hb + sA[i] + k0, lds + b * 8192 + ldsO[i]);
#pragma unroll
    for (int i = 0; i < 2; ++i)
      gld16(w2b + sB[i] + k0, lds + 16384 + b * 8192 + ldsO[i]);
  };

  stage(0, 0);
  __syncthreads();

  int b = 0;
  for (int kt = 0; kt < FDIM / 32; ++kt) {
    const int nk = (kt + 1) * 32;
    if (nk < FDIM) stage(nk, b ^ 1);
    s16x8 af[4], bf[4];
#pragma unroll
    for (int mi = 0; mi < 4; ++mi)
      af[mi] = *(const s16x8*)(lds + b * 8192 + aoff + mi * 1024);
#pragma unroll
    for (int ni = 0; ni < 4; ++ni)
      bf[ni] = *(const s16x8*)(lds + b * 8192 + boff + ni * 1024);
#pragma unroll
    for (int mi = 0; mi < 4; ++mi)
#pragma unroll
      for (int ni = 0; ni < 4; ++ni)
        acc[mi][ni] = __builtin_amdgcn_mfma_f32_16x16x32_bf16(
            af[mi], bf[ni], acc[mi][ni], 0, 0, 0);
    __syncthreads();
    b ^= 1;
  }

  const int erow = (lane >> 4) * 4;
  const int ecol = lane & 15;
#pragma unroll
  for (int mi = 0; mi < 4; ++mi)
#pragma unroll
    for (int j = 0; j < 4; ++j) {
      const int i = mt * 128 + wr * 64 + mi * 16 + erow + j;
      if (i < count) {
        const uint32_t info = (uint32_t)lst[i];
        const int tok = (int)(info & 0x7fffffffu);
        const int slot = (int)(info >> 31);
        const float wt = ewts[e * N_TOK + i];
        float* prow = part + ((size_t)slot * N_TOK + tok) * 1024;
#pragma unroll
        for (int ni = 0; ni < 4; ++ni) {
          const int cb = bn0 + wc * 64 + ni * 16 + ecol;
          prow[cb] = wt * acc[mi][ni][j];
        }
      }
    }
}

extern "C" void kernel_launch(void* const* d_in, const int* in_sizes, int n_in,
                              void* d_out, int out_size, void* d_ws, size_t ws_size,
                              hipStream_t stream) {
  const float* stm = (const float*)d_in[0];
  const float* gw = (const float*)d_in[1];
  const float* w1 = (const float*)d_in[2];
  const float* w2 = (const float*)d_in[3];
  const float* w3 = (const float*)d_in[4];
  float* out = (float*)d_out;
  char* ws = (char*)d_ws;

  __hip_bfloat16* xb = (__hip_bfloat16*)(ws + XB_OFF);
  __hip_bfloat16* hb = (__hip_bfloat16*)(ws + HB_OFF);
  __hip_bfloat16* wb1 = (__hip_bfloat16*)(ws + WB1_OFF);
  __hip_bfloat16* wb3 = (__hip_bfloat16*)(ws + WB3_OFF);
  float* part = (float*)(ws + WB3_OFF);   // down-partials reuse wb3 (dead then)
  int* cnt = (int*)(ws + CNT_OFF);
  int* ebase = (int*)(ws + EBASE_OFF);
  int* elist = (int*)(ws + ELIST_OFF);
  float* ewts = (float*)(ws + EWTS_OFF);

  init_k<<<1, 64, 0, stream>>>(cnt);
  router_k<<<N_TOK, 256, 0, stream>>>(stm, gw, xb, cnt, elist, ewts);
  scan_k<<<1, 64, 0, stream>>>(cnt, ebase);

  const dim3 gUp(16, 64, 8);   // (N-panels/half, M-tiles, experts)
  const dim3 gDn(8, 64, 8);

  // fused gate+up, F-half 0
  convW_k<<<2048, 256, 0, stream>>>(w1, wb1, 0, 2048, FDIM, DIM);
  convW_k<<<2048, 256, 0, stream>>>(w3, wb3, 0, 2048, FDIM, DIM);
  moe_up_k<<<gUp, 256, 0, stream>>>(xb, wb1, wb3, hb, cnt, ebase, elist, 0);
  // fused gate+up, F-half 1
  convW_k<<<2048, 256, 0, stream>>>(w1, wb1, 2048, 2048, FDIM, DIM);
  convW_k<<<2048, 256, 0, stream>>>(w3, wb3, 2048, 2048, FDIM, DIM);
  moe_up_k<<<gUp, 256, 0, stream>>>(xb, wb1, wb3, hb, cnt, ebase, elist, 2048);

  // down, D-half 0: w2 rows [0,1024) -> wb1; partials -> wb3 region; combine
  convW_k<<<2048, 256, 0, stream>>>(w2, wb1, 0, 1024, DIM, FDIM);
  moe_down_k<<<gDn, 256, 0, stream>>>(hb, wb1, part, cnt, ebase, elist, ewts);
  combine_k<<<8192, 256, 0, stream>>>(part, out, 0);
  // down, D-half 1
  convW_k<<<2048, 256, 0, stream>>>(w2, wb1, 1024, 1024, DIM, FDIM);
  moe_down_k<<<gDn, 256, 0, stream>>>(hb, wb1, part, cnt, ebase, elist, ewts);
  combine_k<<<8192, 256, 0, stream>>>(part, out, 1024);
}

// Round 11
// 1428.257 us; speedup vs baseline: 1.3240x; 1.3240x over previous
//
#include <hip/hip_runtime.h>
#include <hip/hip_bf16.h>
#include <stdint.h>

#define N_TOK 8192
#define DIM   2048
#define FDIM  4096
#define NEXP  8

// ---- ws layout (bytes) ---- total EXACTLY 310,902,912 = round-1 proven floor
#define XB_OFF   0ull                        // bf16 x  [8192][2048]    33,554,432
#define HB_OFF   33554432ull                 // bf16 h  [17408][4096]  142,606,336
#define WB1_OFF  176160768ull                // bf16 w1 half; later w2 FULL (134MB, spans wb1+wb3)
#define WB3_OFF  243269632ull                // bf16 w3 half            67,108,864
#define META_OFF 310378496ull
#define CNT_OFF   (META_OFF)                 // int[8] (64B)
#define EBASE_OFF (META_OFF + 64ull)         // int[8] (64B)
#define ELIST_OFF (META_OFF + 128ull)        // int[8][8192]  262,144
#define EWTS_OFF  (ELIST_OFF + 262144ull)    // f32[8][8192]  262,144  -> end 310,902,912

typedef float f32x4 __attribute__((ext_vector_type(4)));
typedef short s16x8 __attribute__((ext_vector_type(8)));

__device__ __forceinline__ uint32_t pkbf(float a, float b) {
  uint32_t ua = __builtin_bit_cast(uint32_t, a) + 0x8000u;
  uint32_t ub = __builtin_bit_cast(uint32_t, b) + 0x8000u;
  return (ua >> 16) | (ub & 0xffff0000u);
}

__device__ __forceinline__ void gld16(const void* g, void* l) {
  __builtin_amdgcn_global_load_lds(
      (__attribute__((address_space(1))) void*)g,
      (__attribute__((address_space(3))) void*)l, 16, 0, 0);
}

__global__ void zero_out_k(float* out) {
  const size_t i = ((size_t)blockIdx.x * 256 + threadIdx.x) * 4;
  *(float4*)(out + i) = make_float4(0.f, 0.f, 0.f, 0.f);
}

__global__ void init_k(int* cnt) {
  if (threadIdx.x < NEXP) cnt[threadIdx.x] = 0;
}

__global__ void router_k(const float* __restrict__ x, const float* __restrict__ gw,
                         __hip_bfloat16* __restrict__ xb, int* __restrict__ cnt,
                         int* __restrict__ elist, float* __restrict__ ewts) {
  const int n = blockIdx.x;
  const int t = threadIdx.x;
  const float* xr = x + (size_t)n * DIM;
  const float4 v0 = *(const float4*)(xr + t * 8);
  const float4 v1 = *(const float4*)(xr + t * 8 + 4);
  uint4 u;
  u.x = pkbf(v0.x, v0.y); u.y = pkbf(v0.z, v0.w);
  u.z = pkbf(v1.x, v1.y); u.w = pkbf(v1.z, v1.w);
  *(uint4*)(xb + (size_t)n * DIM + t * 8) = u;

  float p[NEXP];
#pragma unroll
  for (int e = 0; e < NEXP; ++e) {
    const float* g = gw + e * DIM + t * 8;
    const float4 g0 = *(const float4*)g;
    const float4 g1 = *(const float4*)(g + 4);
    p[e] = v0.x * g0.x + v0.y * g0.y + v0.z * g0.z + v0.w * g0.w +
           v1.x * g1.x + v1.y * g1.y + v1.z * g1.z + v1.w * g1.w;
  }
#pragma unroll
  for (int off = 32; off >= 1; off >>= 1)
#pragma unroll
    for (int e = 0; e < NEXP; ++e) p[e] += __shfl_xor(p[e], off, 64);

  __shared__ float red[4][NEXP];
  const int lane = t & 63, wv = t >> 6;
  if (lane == 0) {
#pragma unroll
    for (int e = 0; e < NEXP; ++e) red[wv][e] = p[e];
  }
  __syncthreads();
  if (t == 0) {
    float l0 = -1e30f, l1 = -1e30f;
    int e0 = 0, e1 = 0;
#pragma unroll
    for (int e = 0; e < NEXP; ++e) {
      float v = red[0][e] + red[1][e] + red[2][e] + red[3][e];
      if (v > l0) { l1 = l0; e1 = e0; l0 = v; e0 = e; }
      else if (v > l1) { l1 = v; e1 = e; }
    }
    const float ed = expf(l1 - l0);
    const float inv = 1.f / (1.f + ed);
    int s0 = atomicAdd(cnt + e0, 1);
    elist[e0 * N_TOK + s0] = n;
    ewts[e0 * N_TOK + s0] = inv;
    int s1 = atomicAdd(cnt + e1, 1);
    elist[e1 * N_TOK + s1] = (int)((uint32_t)n | 0x80000000u);
    ewts[e1 * N_TOK + s1] = ed * inv;
  }
}

__global__ void scan_k(const int* __restrict__ cnt, int* __restrict__ ebase) {
  if (threadIdx.x == 0 && blockIdx.x == 0) {
    int b = 0;
    for (int e = 0; e < NEXP; ++e) { ebase[e] = b; b += (cnt[e] + 127) & ~127; }
  }
}

// convert rows [r0, r0+nrh) of each expert's [rtot][kd] fp32 matrix -> bf16 [e][nrh][kd]
__global__ void convW_k(const float* __restrict__ src, __hip_bfloat16* __restrict__ dst,
                        int r0, int nrh, int rtot, int kd) {
  const int cpr = kd / 8;
  const int total = NEXP * nrh * cpr;
  for (int i = blockIdx.x * blockDim.x + threadIdx.x; i < total;
       i += gridDim.x * blockDim.x) {
    const int e = i / (nrh * cpr);
    const int rem = i - e * nrh * cpr;
    const int lr = rem / cpr;
    const int c = rem - lr * cpr;
    const float* s = src + ((size_t)e * rtot + r0 + lr) * (size_t)kd + c * 8;
    const float4 a = *(const float4*)s;
    const float4 b = *(const float4*)(s + 4);
    uint4 u;
    u.x = pkbf(a.x, a.y); u.y = pkbf(a.z, a.w);
    u.z = pkbf(b.x, b.y); u.w = pkbf(b.z, b.w);
    *(uint4*)(dst + ((size_t)e * nrh + lr) * (size_t)kd + c * 8) = u;
  }
}

// ============================================================================
// Fused gate+up grouped GEMM — ROUND-9 EXACT (335 us/half, MfmaUtil 38%,
// no spill at launch_bounds(256,2) / VGPR 104). Per 128x128 tile:
// h = silu(x@w1h^T) * (x@w3h^T). BK=32, 4 waves, 2-stage LDS dbuf, all
// operands bf16 via global_load_lds w=16, plain 2-barrier K-loop.
// LDS 48KB: A@0, B1@16384, B3@32768 (2x8KB each).
// Swizzle (both sides): row r slot s holds src granule s^((r>>1)&3).
// ============================================================================
__global__ __launch_bounds__(256, 2) void moe_up_k(
    const __hip_bfloat16* __restrict__ xb, const __hip_bfloat16* __restrict__ w1b,
    const __hip_bfloat16* __restrict__ w3b, __hip_bfloat16* __restrict__ hb,
    const int* __restrict__ cnt, const int* __restrict__ ebase,
    const int* __restrict__ elist, int noff) {
  const int e = blockIdx.z;
  const int count = cnt[e];
  const int mt = blockIdx.y;
  if (mt * 128 >= count) return;
  const int bn0 = blockIdx.x * 128;          // col base within half
  const int ncol0 = noff + bn0;              // global F col base

  __shared__ char lds[49152];
  const int t = threadIdx.x;
  const int lane = t & 63, wv = t >> 6;
  const int wr = wv >> 1, wc = wv & 1;
  const int* lst = elist + e * N_TOK;
  const size_t hrow0 = (size_t)ebase[e] + (size_t)mt * 128;

  const int r0 = t >> 2;
  const int ks = (t & 3) ^ ((r0 >> 1) & 3);   // pre-swizzled source granule
  size_t sA[2], sB1[2];
  int ldsO[2];
#pragma unroll
  for (int i = 0; i < 2; ++i) {
    const int r = r0 + i * 64;
    int idx = mt * 128 + r;
    if (idx >= count) idx = 0;                 // clamp pad rows
    const size_t tok = (size_t)(lst[idx] & 0x7fffffff);
    sA[i] = tok * DIM + ks * 8;
    sB1[i] = ((size_t)e * 2048 + bn0 + r) * DIM + ks * 8;
    ldsO[i] = i * 4096 + wv * 1024;            // + lane*16 applied by HW
  }

  const int fr = lane & 15;
  const int swzc = ((lane >> 4) ^ ((fr >> 1) & 3)) << 4;
  const int aoff = (wr * 64 + fr) * 64 + swzc;
  const int boff = (wc * 64 + fr) * 64 + swzc;

  f32x4 accG[4][4], accU[4][4];
#pragma unroll
  for (int mi = 0; mi < 4; ++mi)
#pragma unroll
    for (int ni = 0; ni < 4; ++ni) {
      accG[mi][ni] = {0.f, 0.f, 0.f, 0.f};
      accU[mi][ni] = {0.f, 0.f, 0.f, 0.f};
    }

  auto stage = [&](int k0, int b) {
#pragma unroll
    for (int i = 0; i < 2; ++i)
      gld16(xb + sA[i] + k0, lds + b * 8192 + ldsO[i]);
#pragma unroll
    for (int i = 0; i < 2; ++i)
      gld16(w1b + sB1[i] + k0, lds + 16384 + b * 8192 + ldsO[i]);
#pragma unroll
    for (int i = 0; i < 2; ++i)
      gld16(w3b + sB1[i] + k0, lds + 32768 + b * 8192 + ldsO[i]);
  };

  stage(0, 0);
  __syncthreads();

  int b = 0;
  for (int kt = 0; kt < DIM / 32; ++kt) {
    const int nk = (kt + 1) * 32;
    if (nk < DIM) stage(nk, b ^ 1);
    s16x8 af[4], b1f[4], b3f[4];
#pragma unroll
    for (int mi = 0; mi < 4; ++mi)
      af[mi] = *(const s16x8*)(lds + b * 8192 + aoff + mi * 1024);
#pragma unroll
    for (int ni = 0; ni < 4; ++ni) {
      b1f[ni] = *(const s16x8*)(lds + 16384 + b * 8192 + boff + ni * 1024);
      b3f[ni] = *(const s16x8*)(lds + 32768 + b * 8192 + boff + ni * 1024);
    }
#pragma unroll
    for (int mi = 0; mi < 4; ++mi)
#pragma unroll
      for (int ni = 0; ni < 4; ++ni) {
        accG[mi][ni] = __builtin_amdgcn_mfma_f32_16x16x32_bf16(
            af[mi], b1f[ni], accG[mi][ni], 0, 0, 0);
        accU[mi][ni] = __builtin_amdgcn_mfma_f32_16x16x32_bf16(
            af[mi], b3f[ni], accU[mi][ni], 0, 0, 0);
      }
    __syncthreads();
    b ^= 1;
  }

  const int erow = (lane >> 4) * 4;
  const int ecol = lane & 15;
#pragma unroll
  for (int mi = 0; mi < 4; ++mi)
#pragma unroll
    for (int ni = 0; ni < 4; ++ni) {
      const size_t cb = ncol0 + wc * 64 + ni * 16 + ecol;
#pragma unroll
      for (int j = 0; j < 4; ++j) {
        const size_t r = hrow0 + wr * 64 + mi * 16 + erow + j;
        const float g = accG[mi][ni][j];
        const float uu = accU[mi][ni][j];
        const float h = g / (1.f + __expf(-g)) * uu;
        hb[r * FDIM + cb] = __float2bfloat16(h);
      }
    }
}

// ============================================================================
// Fused down grouped GEMM — UP-SHAPED ECONOMICS: per block, a 128x256 output
// tile computed as TWO 128-col w2 panels sharing the staged A (h) tile.
// Per K-step: 6 gld16 + 12 frag reads + 32 MFMA  (= moe_up_k exactly).
// LDS 48KB: A@0, B_panel0@16384, B_panel1@32768. w2 FULL bf16 resident.
// Epilogue: out += we * acc via atomicAdd (exactly 2 commutative fp32 adds
// per out element -> deterministic; out zeroed first).
// ============================================================================
__global__ __launch_bounds__(256, 2) void moe_down_k(
    const __hip_bfloat16* __restrict__ hb, const __hip_bfloat16* __restrict__ w2b,
    float* __restrict__ out, const int* __restrict__ cnt,
    const int* __restrict__ ebase, const int* __restrict__ elist,
    const float* __restrict__ ewts) {
  const int e = blockIdx.z;
  const int count = cnt[e];
  const int mt = blockIdx.y;
  if (mt * 128 >= count) return;
  const int bn0 = blockIdx.x * 256;          // D col base (two 128-panels)

  __shared__ char lds[49152];
  const int t = threadIdx.x;
  const int lane = t & 63, wv = t >> 6;
  const int wr = wv >> 1, wc = wv & 1;
  const int* lst = elist + e * N_TOK;
  const size_t hrow0 = (size_t)ebase[e] + (size_t)mt * 128;

  const int r0 = t >> 2;
  const int ks = (t & 3) ^ ((r0 >> 1) & 3);
  size_t sA[2], sB[2];
  int ldsO[2];
#pragma unroll
  for (int i = 0; i < 2; ++i) {
    const int r = r0 + i * 64;
    sA[i] = (hrow0 + r) * (size_t)FDIM + ks * 8;
    sB[i] = ((size_t)e * 2048 + bn0 + r) * (size_t)FDIM + ks * 8;  // panel0 rows
    ldsO[i] = i * 4096 + wv * 1024;
  }
  const size_t sBp = 128 * (size_t)FDIM;     // +128 rows -> panel1

  const int fr = lane & 15;
  const int swzc = ((lane >> 4) ^ ((fr >> 1) & 3)) << 4;
  const int aoff = (wr * 64 + fr) * 64 + swzc;
  const int boff = (wc * 64 + fr) * 64 + swzc;

  f32x4 accP[2][4][4];
#pragma unroll
  for (int p = 0; p < 2; ++p)
#pragma unroll
    for (int mi = 0; mi < 4; ++mi)
#pragma unroll
      for (int ni = 0; ni < 4; ++ni) accP[p][mi][ni] = {0.f, 0.f, 0.f, 0.f};

  auto stage = [&](int k0, int b) {
#pragma unroll
    for (int i = 0; i < 2; ++i)
      gld16(hb + sA[i] + k0, lds + b * 8192 + ldsO[i]);
#pragma unroll
    for (int i = 0; i < 2; ++i)
      gld16(w2b + sB[i] + k0, lds + 16384 + b * 8192 + ldsO[i]);
#pragma unroll
    for (int i = 0; i < 2; ++i)
      gld16(w2b + sB[i] + sBp + k0, lds + 32768 + b * 8192 + ldsO[i]);
  };

  stage(0, 0);
  __syncthreads();

  int b = 0;
  for (int kt = 0; kt < FDIM / 32; ++kt) {
    const int nk = (kt + 1) * 32;
    if (nk < FDIM) stage(nk, b ^ 1);
    s16x8 af[4], b0f[4], b1f[4];
#pragma unroll
    for (int mi = 0; mi < 4; ++mi)
      af[mi] = *(const s16x8*)(lds + b * 8192 + aoff + mi * 1024);
#pragma unroll
    for (int ni = 0; ni < 4; ++ni) {
      b0f[ni] = *(const s16x8*)(lds + 16384 + b * 8192 + boff + ni * 1024);
      b1f[ni] = *(const s16x8*)(lds + 32768 + b * 8192 + boff + ni * 1024);
    }
#pragma unroll
    for (int mi = 0; mi < 4; ++mi)
#pragma unroll
      for (int ni = 0; ni < 4; ++ni) {
        accP[0][mi][ni] = __builtin_amdgcn_mfma_f32_16x16x32_bf16(
            af[mi], b0f[ni], accP[0][mi][ni], 0, 0, 0);
        accP[1][mi][ni] = __builtin_amdgcn_mfma_f32_16x16x32_bf16(
            af[mi], b1f[ni], accP[1][mi][ni], 0, 0, 0);
      }
    __syncthreads();
    b ^= 1;
  }

  const int erow = (lane >> 4) * 4;
  const int ecol = lane & 15;
#pragma unroll
  for (int mi = 0; mi < 4; ++mi)
#pragma unroll
    for (int j = 0; j < 4; ++j) {
      const int i = mt * 128 + wr * 64 + mi * 16 + erow + j;
      if (i < count) {
        const uint32_t info = (uint32_t)lst[i];
        const int tok = (int)(info & 0x7fffffffu);
        const float wt = ewts[e * N_TOK + i];
        float* prow = out + (size_t)tok * DIM;
#pragma unroll
        for (int p = 0; p < 2; ++p)
#pragma unroll
          for (int ni = 0; ni < 4; ++ni) {
            const int cb = bn0 + p * 128 + wc * 64 + ni * 16 + ecol;
            atomicAdd(prow + cb, wt * accP[p][mi][ni][j]);
          }
      }
    }
}

extern "C" void kernel_launch(void* const* d_in, const int* in_sizes, int n_in,
                              void* d_out, int out_size, void* d_ws, size_t ws_size,
                              hipStream_t stream) {
  const float* stm = (const float*)d_in[0];
  const float* gw = (const float*)d_in[1];
  const float* w1 = (const float*)d_in[2];
  const float* w2 = (const float*)d_in[3];
  const float* w3 = (const float*)d_in[4];
  float* out = (float*)d_out;
  char* ws = (char*)d_ws;

  __hip_bfloat16* xb = (__hip_bfloat16*)(ws + XB_OFF);
  __hip_bfloat16* hb = (__hip_bfloat16*)(ws + HB_OFF);
  __hip_bfloat16* wb1 = (__hip_bfloat16*)(ws + WB1_OFF);
  __hip_bfloat16* wb3 = (__hip_bfloat16*)(ws + WB3_OFF);
  __hip_bfloat16* w2full = (__hip_bfloat16*)(ws + WB1_OFF);  // 134MB spans wb1+wb3
  int* cnt = (int*)(ws + CNT_OFF);
  int* ebase = (int*)(ws + EBASE_OFF);
  int* elist = (int*)(ws + ELIST_OFF);
  float* ewts = (float*)(ws + EWTS_OFF);

  init_k<<<1, 64, 0, stream>>>(cnt);
  router_k<<<N_TOK, 256, 0, stream>>>(stm, gw, xb, cnt, elist, ewts);
  scan_k<<<1, 64, 0, stream>>>(cnt, ebase);
  zero_out_k<<<N_TOK * DIM / 1024, 256, 0, stream>>>(out);

  const dim3 gUp(16, 64, 8);   // (N-panels/half, M-tiles, experts)
  const dim3 gDn(8, 64, 8);    // (256-col D panels, M-tiles, experts)

  // fused gate+up, F-half 0
  convW_k<<<2048, 256, 0, stream>>>(w1, wb1, 0, 2048, FDIM, DIM);
  convW_k<<<2048, 256, 0, stream>>>(w3, wb3, 0, 2048, FDIM, DIM);
  moe_up_k<<<gUp, 256, 0, stream>>>(xb, wb1, wb3, hb, cnt, ebase, elist, 0);
  // fused gate+up, F-half 1
  convW_k<<<2048, 256, 0, stream>>>(w1, wb1, 2048, 2048, FDIM, DIM);
  convW_k<<<2048, 256, 0, stream>>>(w3, wb3, 2048, 2048, FDIM, DIM);
  moe_up_k<<<gUp, 256, 0, stream>>>(xb, wb1, wb3, hb, cnt, ebase, elist, 2048);

  // down: full w2 -> bf16 (wb1+wb3 region, both dead), then one fused launch
  convW_k<<<4096, 256, 0, stream>>>(w2, w2full, 0, 2048, DIM, FDIM);
  moe_down_k<<<gDn, 256, 0, stream>>>(hb, w2full, out, cnt, ebase, elist, ewts);
}

// Round 12
// 1384.457 us; speedup vs baseline: 1.3659x; 1.0316x over previous
//
#include <hip/hip_runtime.h>
#include <hip/hip_bf16.h>
#include <stdint.h>

#define N_TOK 8192
#define DIM   2048
#define FDIM  4096
#define NEXP  8

// ---- ws layout (bytes) ---- total EXACTLY 310,902,912 = round-1 proven floor
#define XB_OFF   0ull                        // bf16 x  [8192][2048]    33,554,432
#define HB_OFF   33554432ull                 // bf16 h  [17408][4096]  142,606,336
#define WB1_OFF  176160768ull                // bf16 w1 half; later w2 FULL (134MB, spans wb1+wb3)
#define WB3_OFF  243269632ull                // bf16 w3 half            67,108,864
#define META_OFF 310378496ull
#define CNT_OFF   (META_OFF)                 // int[8] (64B)
#define EBASE_OFF (META_OFF + 64ull)         // int[8] (64B)
#define ELIST_OFF (META_OFF + 128ull)        // int[8][8192]  262,144
#define EWTS_OFF  (ELIST_OFF + 262144ull)    // f32[8][8192]  262,144  -> end 310,902,912

typedef float f32x4 __attribute__((ext_vector_type(4)));
typedef short s16x8 __attribute__((ext_vector_type(8)));

__device__ __forceinline__ uint32_t pkbf(float a, float b) {
  uint32_t ua = __builtin_bit_cast(uint32_t, a) + 0x8000u;
  uint32_t ub = __builtin_bit_cast(uint32_t, b) + 0x8000u;
  return (ua >> 16) | (ub & 0xffff0000u);
}

__device__ __forceinline__ void gld16(const void* g, void* l) {
  __builtin_amdgcn_global_load_lds(
      (__attribute__((address_space(1))) void*)g,
      (__attribute__((address_space(3))) void*)l, 16, 0, 0);
}

__global__ void zero_out_k(float* out) {
  const size_t i = ((size_t)blockIdx.x * 256 + threadIdx.x) * 4;
  *(float4*)(out + i) = make_float4(0.f, 0.f, 0.f, 0.f);
}

__global__ void init_k(int* cnt) {
  if (threadIdx.x < NEXP) cnt[threadIdx.x] = 0;
}

__global__ void router_k(const float* __restrict__ x, const float* __restrict__ gw,
                         __hip_bfloat16* __restrict__ xb, int* __restrict__ cnt,
                         int* __restrict__ elist, float* __restrict__ ewts) {
  const int n = blockIdx.x;
  const int t = threadIdx.x;
  const float* xr = x + (size_t)n * DIM;
  const float4 v0 = *(const float4*)(xr + t * 8);
  const float4 v1 = *(const float4*)(xr + t * 8 + 4);
  uint4 u;
  u.x = pkbf(v0.x, v0.y); u.y = pkbf(v0.z, v0.w);
  u.z = pkbf(v1.x, v1.y); u.w = pkbf(v1.z, v1.w);
  *(uint4*)(xb + (size_t)n * DIM + t * 8) = u;

  float p[NEXP];
#pragma unroll
  for (int e = 0; e < NEXP; ++e) {
    const float* g = gw + e * DIM + t * 8;
    const float4 g0 = *(const float4*)g;
    const float4 g1 = *(const float4*)(g + 4);
    p[e] = v0.x * g0.x + v0.y * g0.y + v0.z * g0.z + v0.w * g0.w +
           v1.x * g1.x + v1.y * g1.y + v1.z * g1.z + v1.w * g1.w;
  }
#pragma unroll
  for (int off = 32; off >= 1; off >>= 1)
#pragma unroll
    for (int e = 0; e < NEXP; ++e) p[e] += __shfl_xor(p[e], off, 64);

  __shared__ float red[4][NEXP];
  const int lane = t & 63, wv = t >> 6;
  if (lane == 0) {
#pragma unroll
    for (int e = 0; e < NEXP; ++e) red[wv][e] = p[e];
  }
  __syncthreads();
  if (t == 0) {
    float l0 = -1e30f, l1 = -1e30f;
    int e0 = 0, e1 = 0;
#pragma unroll
    for (int e = 0; e < NEXP; ++e) {
      float v = red[0][e] + red[1][e] + red[2][e] + red[3][e];
      if (v > l0) { l1 = l0; e1 = e0; l0 = v; e0 = e; }
      else if (v > l1) { l1 = v; e1 = e; }
    }
    const float ed = expf(l1 - l0);
    const float inv = 1.f / (1.f + ed);
    int s0 = atomicAdd(cnt + e0, 1);
    elist[e0 * N_TOK + s0] = n;
    ewts[e0 * N_TOK + s0] = inv;
    int s1 = atomicAdd(cnt + e1, 1);
    elist[e1 * N_TOK + s1] = (int)((uint32_t)n | 0x80000000u);
    ewts[e1 * N_TOK + s1] = ed * inv;
  }
}

__global__ void scan_k(const int* __restrict__ cnt, int* __restrict__ ebase) {
  if (threadIdx.x == 0 && blockIdx.x == 0) {
    int b = 0;
    for (int e = 0; e < NEXP; ++e) { ebase[e] = b; b += (cnt[e] + 127) & ~127; }
  }
}

// convert rows [r0, r0+nrh) of each expert's [rtot][kd] fp32 matrix -> bf16 [e][nrh][kd]
__global__ void convW_k(const float* __restrict__ src, __hip_bfloat16* __restrict__ dst,
                        int r0, int nrh, int rtot, int kd) {
  const int cpr = kd / 8;
  const int total = NEXP * nrh * cpr;
  for (int i = blockIdx.x * blockDim.x + threadIdx.x; i < total;
       i += gridDim.x * blockDim.x) {
    const int e = i / (nrh * cpr);
    const int rem = i - e * nrh * cpr;
    const int lr = rem / cpr;
    const int c = rem - lr * cpr;
    const float* s = src + ((size_t)e * rtot + r0 + lr) * (size_t)kd + c * 8;
    const float4 a = *(const float4*)s;
    const float4 b = *(const float4*)(s + 4);
    uint4 u;
    u.x = pkbf(a.x, a.y); u.y = pkbf(a.z, a.w);
    u.z = pkbf(b.x, b.y); u.w = pkbf(b.z, b.w);
    *(uint4*)(dst + ((size_t)e * nrh + lr) * (size_t)kd + c * 8) = u;
  }
}

// ============================================================================
// Fused gate+up grouped GEMM — ROUND-9/11 EXACT (proven 335 us/half, no spill).
// ============================================================================
__global__ __launch_bounds__(256, 2) void moe_up_k(
    const __hip_bfloat16* __restrict__ xb, const __hip_bfloat16* __restrict__ w1b,
    const __hip_bfloat16* __restrict__ w3b, __hip_bfloat16* __restrict__ hb,
    const int* __restrict__ cnt, const int* __restrict__ ebase,
    const int* __restrict__ elist, int noff) {
  const int e = blockIdx.z;
  const int count = cnt[e];
  const int mt = blockIdx.y;
  if (mt * 128 >= count) return;
  const int bn0 = blockIdx.x * 128;          // col base within half
  const int ncol0 = noff + bn0;              // global F col base

  __shared__ char lds[49152];
  const int t = threadIdx.x;
  const int lane = t & 63, wv = t >> 6;
  const int wr = wv >> 1, wc = wv & 1;
  const int* lst = elist + e * N_TOK;
  const size_t hrow0 = (size_t)ebase[e] + (size_t)mt * 128;

  const int r0 = t >> 2;
  const int ks = (t & 3) ^ ((r0 >> 1) & 3);   // pre-swizzled source granule
  size_t sA[2], sB1[2];
  int ldsO[2];
#pragma unroll
  for (int i = 0; i < 2; ++i) {
    const int r = r0 + i * 64;
    int idx = mt * 128 + r;
    if (idx >= count) idx = 0;                 // clamp pad rows
    const size_t tok = (size_t)(lst[idx] & 0x7fffffff);
    sA[i] = tok * DIM + ks * 8;
    sB1[i] = ((size_t)e * 2048 + bn0 + r) * DIM + ks * 8;
    ldsO[i] = i * 4096 + wv * 1024;            // + lane*16 applied by HW
  }

  const int fr = lane & 15;
  const int swzc = ((lane >> 4) ^ ((fr >> 1) & 3)) << 4;
  const int aoff = (wr * 64 + fr) * 64 + swzc;
  const int boff = (wc * 64 + fr) * 64 + swzc;

  f32x4 accG[4][4], accU[4][4];
#pragma unroll
  for (int mi = 0; mi < 4; ++mi)
#pragma unroll
    for (int ni = 0; ni < 4; ++ni) {
      accG[mi][ni] = {0.f, 0.f, 0.f, 0.f};
      accU[mi][ni] = {0.f, 0.f, 0.f, 0.f};
    }

  auto stage = [&](int k0, int b) {
#pragma unroll
    for (int i = 0; i < 2; ++i)
      gld16(xb + sA[i] + k0, lds + b * 8192 + ldsO[i]);
#pragma unroll
    for (int i = 0; i < 2; ++i)
      gld16(w1b + sB1[i] + k0, lds + 16384 + b * 8192 + ldsO[i]);
#pragma unroll
    for (int i = 0; i < 2; ++i)
      gld16(w3b + sB1[i] + k0, lds + 32768 + b * 8192 + ldsO[i]);
  };

  stage(0, 0);
  __syncthreads();

  int b = 0;
  for (int kt = 0; kt < DIM / 32; ++kt) {
    const int nk = (kt + 1) * 32;
    if (nk < DIM) stage(nk, b ^ 1);
    s16x8 af[4], b1f[4], b3f[4];
#pragma unroll
    for (int mi = 0; mi < 4; ++mi)
      af[mi] = *(const s16x8*)(lds + b * 8192 + aoff + mi * 1024);
#pragma unroll
    for (int ni = 0; ni < 4; ++ni) {
      b1f[ni] = *(const s16x8*)(lds + 16384 + b * 8192 + boff + ni * 1024);
      b3f[ni] = *(const s16x8*)(lds + 32768 + b * 8192 + boff + ni * 1024);
    }
#pragma unroll
    for (int mi = 0; mi < 4; ++mi)
#pragma unroll
      for (int ni = 0; ni < 4; ++ni) {
        accG[mi][ni] = __builtin_amdgcn_mfma_f32_16x16x32_bf16(
            af[mi], b1f[ni], accG[mi][ni], 0, 0, 0);
        accU[mi][ni] = __builtin_amdgcn_mfma_f32_16x16x32_bf16(
            af[mi], b3f[ni], accU[mi][ni], 0, 0, 0);
      }
    __syncthreads();
    b ^= 1;
  }

  const int erow = (lane >> 4) * 4;
  const int ecol = lane & 15;
#pragma unroll
  for (int mi = 0; mi < 4; ++mi)
#pragma unroll
    for (int ni = 0; ni < 4; ++ni) {
      const size_t cb = ncol0 + wc * 64 + ni * 16 + ecol;
#pragma unroll
      for (int j = 0; j < 4; ++j) {
        const size_t r = hrow0 + wr * 64 + mi * 16 + erow + j;
        const float g = accG[mi][ni][j];
        const float uu = accU[mi][ni][j];
        const float h = g / (1.f + __expf(-g)) * uu;
        hb[r * FDIM + cb] = __float2bfloat16(h);
      }
    }
}

// ============================================================================
// Fused down grouped GEMM — 3-STAGE pipeline + counted vmcnt(6):
// per block a 128x256 output tile (two w2 panels sharing the staged h tile).
// Sources (h 134MB + w2 134MB) exceed LLC -> HBM-latency staging; 3 LDS
// buffers (3 x 24KB = 72KB) give a 2-iteration latency budget, and the
// loop never drains vmcnt to 0: each iter issues tile t+2 (6 gld16, clamped
// for uniform counts), then vmcnt(6) + raw s_barrier publishes tile t+1 while
// tile t+2 stays in flight.
// Grid (x=expert, y=mtile, z=panel): linear%8 = expert -> each XCD owns one
// expert; its 64 concurrent blocks share one 2MB w2 panel (L2-resident).
// Epilogue: out += we*acc via atomicAdd (2 commutative adds/elem, determ.).
// ============================================================================
__global__ __launch_bounds__(256, 2) void moe_down_k(
    const __hip_bfloat16* __restrict__ hb, const __hip_bfloat16* __restrict__ w2b,
    float* __restrict__ out, const int* __restrict__ cnt,
    const int* __restrict__ ebase, const int* __restrict__ elist,
    const float* __restrict__ ewts) {
  constexpr int NT = FDIM / 32;              // 128 K-steps
  const int e = blockIdx.x;                  // expert on XCD e
  const int count = cnt[e];
  const int mt = blockIdx.y;
  if (mt * 128 >= count) return;
  const int bn0 = blockIdx.z * 256;          // D col base (two 128-panels)

  __shared__ char lds[73728];                // 3 bufs x (A 8K | B0 8K | B1 8K)
  const int t = threadIdx.x;
  const int lane = t & 63, wv = t >> 6;
  const int wr = wv >> 1, wc = wv & 1;
  const int* lst = elist + e * N_TOK;
  const size_t hrow0 = (size_t)ebase[e] + (size_t)mt * 128;

  const int r0 = t >> 2;
  const int ks = (t & 3) ^ ((r0 >> 1) & 3);
  size_t sA[2], sB[2];
  int ldsO[2];
#pragma unroll
  for (int i = 0; i < 2; ++i) {
    const int r = r0 + i * 64;
    sA[i] = (hrow0 + r) * (size_t)FDIM + ks * 8;
    sB[i] = ((size_t)e * 2048 + bn0 + r) * (size_t)FDIM + ks * 8;  // panel0 rows
    ldsO[i] = i * 4096 + wv * 1024;
  }
  const size_t sBp = 128 * (size_t)FDIM;     // +128 rows -> panel1

  const int fr = lane & 15;
  const int swzc = ((lane >> 4) ^ ((fr >> 1) & 3)) << 4;
  const int aoff = (wr * 64 + fr) * 64 + swzc;
  const int boff = (wc * 64 + fr) * 64 + swzc;

  f32x4 accP[2][4][4];
#pragma unroll
  for (int p = 0; p < 2; ++p)
#pragma unroll
    for (int mi = 0; mi < 4; ++mi)
#pragma unroll
      for (int ni = 0; ni < 4; ++ni) accP[p][mi][ni] = {0.f, 0.f, 0.f, 0.f};

  auto stage = [&](int kt, int b) {          // 6 gld16, always
    const int k0 = kt * 32;
    char* base = lds + b * 24576;
#pragma unroll
    for (int i = 0; i < 2; ++i)
      gld16(hb + sA[i] + k0, base + ldsO[i]);
#pragma unroll
    for (int i = 0; i < 2; ++i)
      gld16(w2b + sB[i] + k0, base + 8192 + ldsO[i]);
#pragma unroll
    for (int i = 0; i < 2; ++i)
      gld16(w2b + sB[i] + sBp + k0, base + 16384 + ldsO[i]);
  };

  // prologue: tiles 0,1 -> bufs 0,1; publish tile 0 (keep tile 1 in flight)
  stage(0, 0);
  stage(1, 1);
  asm volatile("s_waitcnt vmcnt(6)" ::: "memory");
  __builtin_amdgcn_sched_barrier(0);
  __builtin_amdgcn_s_barrier();
  __builtin_amdgcn_sched_barrier(0);

  int bR = 0, bS = 2;                        // read buf, stage buf
#pragma unroll 3
  for (int kt = 0; kt < NT; ++kt) {
    const int t2 = (kt + 2 < NT) ? kt + 2 : NT - 1;   // clamp: uniform counts
    stage(t2, bS);
    char* base = lds + bR * 24576;
    s16x8 af[4], b0f[4], b1f[4];
#pragma unroll
    for (int mi = 0; mi < 4; ++mi)
      af[mi] = *(const s16x8*)(base + aoff + mi * 1024);
#pragma unroll
    for (int ni = 0; ni < 4; ++ni) {
      b0f[ni] = *(const s16x8*)(base + 8192 + boff + ni * 1024);
      b1f[ni] = *(const s16x8*)(base + 16384 + boff + ni * 1024);
    }
#pragma unroll
    for (int mi = 0; mi < 4; ++mi)
#pragma unroll
      for (int ni = 0; ni < 4; ++ni) {
        accP[0][mi][ni] = __builtin_amdgcn_mfma_f32_16x16x32_bf16(
            af[mi], b0f[ni], accP[0][mi][ni], 0, 0, 0);
        accP[1][mi][ni] = __builtin_amdgcn_mfma_f32_16x16x32_bf16(
            af[mi], b1f[ni], accP[1][mi][ni], 0, 0, 0);
      }
    asm volatile("s_waitcnt vmcnt(6)" ::: "memory");   // tile kt+1 published
    __builtin_amdgcn_sched_barrier(0);
    __builtin_amdgcn_s_barrier();
    __builtin_amdgcn_sched_barrier(0);
    bR = (bR == 2) ? 0 : bR + 1;
    bS = (bS == 2) ? 0 : bS + 1;
  }

  const int erow = (lane >> 4) * 4;
  const int ecol = lane & 15;
#pragma unroll
  for (int mi = 0; mi < 4; ++mi)
#pragma unroll
    for (int j = 0; j < 4; ++j) {
      const int i = mt * 128 + wr * 64 + mi * 16 + erow + j;
      if (i < count) {
        const uint32_t info = (uint32_t)lst[i];
        const int tok = (int)(info & 0x7fffffffu);
        const float wt = ewts[e * N_TOK + i];
        float* prow = out + (size_t)tok * DIM;
#pragma unroll
        for (int p = 0; p < 2; ++p)
#pragma unroll
          for (int ni = 0; ni < 4; ++ni) {
            const int cb = bn0 + p * 128 + wc * 64 + ni * 16 + ecol;
            atomicAdd(prow + cb, wt * accP[p][mi][ni][j]);
          }
      }
    }
}

extern "C" void kernel_launch(void* const* d_in, const int* in_sizes, int n_in,
                              void* d_out, int out_size, void* d_ws, size_t ws_size,
                              hipStream_t stream) {
  const float* stm = (const float*)d_in[0];
  const float* gw = (const float*)d_in[1];
  const float* w1 = (const float*)d_in[2];
  const float* w2 = (const float*)d_in[3];
  const float* w3 = (const float*)d_in[4];
  float* out = (float*)d_out;
  char* ws = (char*)d_ws;

  __hip_bfloat16* xb = (__hip_bfloat16*)(ws + XB_OFF);
  __hip_bfloat16* hb = (__hip_bfloat16*)(ws + HB_OFF);
  __hip_bfloat16* wb1 = (__hip_bfloat16*)(ws + WB1_OFF);
  __hip_bfloat16* wb3 = (__hip_bfloat16*)(ws + WB3_OFF);
  __hip_bfloat16* w2full = (__hip_bfloat16*)(ws + WB1_OFF);  // 134MB spans wb1+wb3
  int* cnt = (int*)(ws + CNT_OFF);
  int* ebase = (int*)(ws + EBASE_OFF);
  int* elist = (int*)(ws + ELIST_OFF);
  float* ewts = (float*)(ws + EWTS_OFF);

  init_k<<<1, 64, 0, stream>>>(cnt);
  router_k<<<N_TOK, 256, 0, stream>>>(stm, gw, xb, cnt, elist, ewts);
  scan_k<<<1, 64, 0, stream>>>(cnt, ebase);
  zero_out_k<<<N_TOK * DIM / 1024, 256, 0, stream>>>(out);

  const dim3 gUp(16, 64, 8);   // (N-panels/half, M-tiles, experts)
  const dim3 gDn(8, 64, 8);    // (experts, M-tiles, 256-col D panels)

  // fused gate+up, F-half 0
  convW_k<<<2048, 256, 0, stream>>>(w1, wb1, 0, 2048, FDIM, DIM);
  convW_k<<<2048, 256, 0, stream>>>(w3, wb3, 0, 2048, FDIM, DIM);
  moe_up_k<<<gUp, 256, 0, stream>>>(xb, wb1, wb3, hb, cnt, ebase, elist, 0);
  // fused gate+up, F-half 1
  convW_k<<<2048, 256, 0, stream>>>(w1, wb1, 2048, 2048, FDIM, DIM);
  convW_k<<<2048, 256, 0, stream>>>(w3, wb3, 2048, 2048, FDIM, DIM);
  moe_up_k<<<gUp, 256, 0, stream>>>(xb, wb1, wb3, hb, cnt, ebase, elist, 2048);

  // down: full w2 -> bf16 (wb1+wb3 region, both dead), then one fused launch
  convW_k<<<4096, 256, 0, stream>>>(w2, w2full, 0, 2048, DIM, FDIM);
  moe_down_k<<<gDn, 256, 0, stream>>>(hb, w2full, out, cnt, ebase, elist, ewts);
}

// Round 13
// 1349.126 us; speedup vs baseline: 1.4017x; 1.0262x over previous
//
#include <hip/hip_runtime.h>
#include <hip/hip_bf16.h>
#include <stdint.h>

#define N_TOK 8192
#define DIM   2048
#define FDIM  4096
#define NEXP  8

// ---- ws layout (bytes) ---- total EXACTLY 310,902,912 = round-1 proven floor
#define XB_OFF   0ull                        // bf16 x  [8192][2048]    33,554,432
#define HB_OFF   33554432ull                 // bf16 h  [17408][4096]  142,606,336
#define WB1_OFF  176160768ull                // bf16 w1 half; later w2 FULL (134MB, spans wb1+wb3)
#define WB3_OFF  243269632ull                // bf16 w3 half            67,108,864
#define META_OFF 310378496ull
#define CNT_OFF   (META_OFF)                 // int[8] (64B)
#define EBASE_OFF (META_OFF + 64ull)         // int[8] (64B)
#define ELIST_OFF (META_OFF + 128ull)        // int[8][8192]  262,144
#define EWTS_OFF  (ELIST_OFF + 262144ull)    // f32[8][8192]  262,144  -> end 310,902,912

typedef float f32x4 __attribute__((ext_vector_type(4)));
typedef short s16x8 __attribute__((ext_vector_type(8)));

__device__ __forceinline__ uint32_t pkbf(float a, float b) {
  uint32_t ua = __builtin_bit_cast(uint32_t, a) + 0x8000u;
  uint32_t ub = __builtin_bit_cast(uint32_t, b) + 0x8000u;
  return (ua >> 16) | (ub & 0xffff0000u);
}

__device__ __forceinline__ void gld16(const void* g, void* l) {
  __builtin_amdgcn_global_load_lds(
      (__attribute__((address_space(1))) void*)g,
      (__attribute__((address_space(3))) void*)l, 16, 0, 0);
}

__global__ void zero_out_k(float* out) {
  const size_t i = ((size_t)blockIdx.x * 256 + threadIdx.x) * 4;
  *(float4*)(out + i) = make_float4(0.f, 0.f, 0.f, 0.f);
}

__global__ void init_k(int* cnt) {
  if (threadIdx.x < NEXP) cnt[threadIdx.x] = 0;
}

__global__ void router_k(const float* __restrict__ x, const float* __restrict__ gw,
                         __hip_bfloat16* __restrict__ xb, int* __restrict__ cnt,
                         int* __restrict__ elist, float* __restrict__ ewts) {
  const int n = blockIdx.x;
  const int t = threadIdx.x;
  const float* xr = x + (size_t)n * DIM;
  const float4 v0 = *(const float4*)(xr + t * 8);
  const float4 v1 = *(const float4*)(xr + t * 8 + 4);
  uint4 u;
  u.x = pkbf(v0.x, v0.y); u.y = pkbf(v0.z, v0.w);
  u.z = pkbf(v1.x, v1.y); u.w = pkbf(v1.z, v1.w);
  *(uint4*)(xb + (size_t)n * DIM + t * 8) = u;

  float p[NEXP];
#pragma unroll
  for (int e = 0; e < NEXP; ++e) {
    const float* g = gw + e * DIM + t * 8;
    const float4 g0 = *(const float4*)g;
    const float4 g1 = *(const float4*)(g + 4);
    p[e] = v0.x * g0.x + v0.y * g0.y + v0.z * g0.z + v0.w * g0.w +
           v1.x * g1.x + v1.y * g1.y + v1.z * g1.z + v1.w * g1.w;
  }
#pragma unroll
  for (int off = 32; off >= 1; off >>= 1)
#pragma unroll
    for (int e = 0; e < NEXP; ++e) p[e] += __shfl_xor(p[e], off, 64);

  __shared__ float red[4][NEXP];
  const int lane = t & 63, wv = t >> 6;
  if (lane == 0) {
#pragma unroll
    for (int e = 0; e < NEXP; ++e) red[wv][e] = p[e];
  }
  __syncthreads();
  if (t == 0) {
    float l0 = -1e30f, l1 = -1e30f;
    int e0 = 0, e1 = 0;
#pragma unroll
    for (int e = 0; e < NEXP; ++e) {
      float v = red[0][e] + red[1][e] + red[2][e] + red[3][e];
      if (v > l0) { l1 = l0; e1 = e0; l0 = v; e0 = e; }
      else if (v > l1) { l1 = v; e1 = e; }
    }
    const float ed = expf(l1 - l0);
    const float inv = 1.f / (1.f + ed);
    int s0 = atomicAdd(cnt + e0, 1);
    elist[e0 * N_TOK + s0] = n;
    ewts[e0 * N_TOK + s0] = inv;
    int s1 = atomicAdd(cnt + e1, 1);
    elist[e1 * N_TOK + s1] = (int)((uint32_t)n | 0x80000000u);
    ewts[e1 * N_TOK + s1] = ed * inv;
  }
}

__global__ void scan_k(const int* __restrict__ cnt, int* __restrict__ ebase) {
  if (threadIdx.x == 0 && blockIdx.x == 0) {
    int b = 0;
    for (int e = 0; e < NEXP; ++e) { ebase[e] = b; b += (cnt[e] + 127) & ~127; }
  }
}

// convert rows [r0, r0+nrh) of each expert's [rtot][kd] fp32 matrix -> bf16 [e][nrh][kd]
__global__ void convW_k(const float* __restrict__ src, __hip_bfloat16* __restrict__ dst,
                        int r0, int nrh, int rtot, int kd) {
  const int cpr = kd / 8;
  const int total = NEXP * nrh * cpr;
  for (int i = blockIdx.x * blockDim.x + threadIdx.x; i < total;
       i += gridDim.x * blockDim.x) {
    const int e = i / (nrh * cpr);
    const int rem = i - e * nrh * cpr;
    const int lr = rem / cpr;
    const int c = rem - lr * cpr;
    const float* s = src + ((size_t)e * rtot + r0 + lr) * (size_t)kd + c * 8;
    const float4 a = *(const float4*)s;
    const float4 b = *(const float4*)(s + 4);
    uint4 u;
    u.x = pkbf(a.x, a.y); u.y = pkbf(a.z, a.w);
    u.z = pkbf(b.x, b.y); u.w = pkbf(b.z, b.w);
    *(uint4*)(dst + ((size_t)e * nrh + lr) * (size_t)kd + c * 8) = u;
  }
}

// ============================================================================
// Fused gate+up grouped GEMM — round-9 economics + round-12-proven 3-STAGE
// pipeline with counted vmcnt(6): per K-step 6 gld16 (A,B1,B3 x2) into one of
// 3 LDS buffers (3 x 24KB = 72KB, 2 blocks/CU); each iter issues tile t+2
// (clamped -> uniform counts), computes tile t, then vmcnt(6)+raw barrier
// publishes tile t+1 while t+2 stays in flight (never drains to 0).
// Swizzle (both sides): row r slot s holds src granule s^((r>>1)&3).
// ============================================================================
__global__ __launch_bounds__(256, 2) void moe_up_k(
    const __hip_bfloat16* __restrict__ xb, const __hip_bfloat16* __restrict__ w1b,
    const __hip_bfloat16* __restrict__ w3b, __hip_bfloat16* __restrict__ hb,
    const int* __restrict__ cnt, const int* __restrict__ ebase,
    const int* __restrict__ elist, int noff) {
  constexpr int NT = DIM / 32;               // 64 K-steps
  const int e = blockIdx.z;
  const int count = cnt[e];
  const int mt = blockIdx.y;
  if (mt * 128 >= count) return;
  const int bn0 = blockIdx.x * 128;          // col base within half
  const int ncol0 = noff + bn0;              // global F col base

  __shared__ char lds[73728];                // 3 bufs x (A 8K | B1 8K | B3 8K)
  const int t = threadIdx.x;
  const int lane = t & 63, wv = t >> 6;
  const int wr = wv >> 1, wc = wv & 1;
  const int* lst = elist + e * N_TOK;
  const size_t hrow0 = (size_t)ebase[e] + (size_t)mt * 128;

  const int r0 = t >> 2;
  const int ks = (t & 3) ^ ((r0 >> 1) & 3);   // pre-swizzled source granule
  size_t sA[2], sB1[2];
  int ldsO[2];
#pragma unroll
  for (int i = 0; i < 2; ++i) {
    const int r = r0 + i * 64;
    int idx = mt * 128 + r;
    if (idx >= count) idx = 0;                 // clamp pad rows
    const size_t tok = (size_t)(lst[idx] & 0x7fffffff);
    sA[i] = tok * DIM + ks * 8;
    sB1[i] = ((size_t)e * 2048 + bn0 + r) * DIM + ks * 8;
    ldsO[i] = i * 4096 + wv * 1024;            // + lane*16 applied by HW
  }

  const int fr = lane & 15;
  const int swzc = ((lane >> 4) ^ ((fr >> 1) & 3)) << 4;
  const int aoff = (wr * 64 + fr) * 64 + swzc;
  const int boff = (wc * 64 + fr) * 64 + swzc;

  f32x4 accG[4][4], accU[4][4];
#pragma unroll
  for (int mi = 0; mi < 4; ++mi)
#pragma unroll
    for (int ni = 0; ni < 4; ++ni) {
      accG[mi][ni] = {0.f, 0.f, 0.f, 0.f};
      accU[mi][ni] = {0.f, 0.f, 0.f, 0.f};
    }

  auto stage = [&](int kt, int b) {            // 6 gld16, always
    const int k0 = kt * 32;
    char* base = lds + b * 24576;
#pragma unroll
    for (int i = 0; i < 2; ++i)
      gld16(xb + sA[i] + k0, base + ldsO[i]);
#pragma unroll
    for (int i = 0; i < 2; ++i)
      gld16(w1b + sB1[i] + k0, base + 8192 + ldsO[i]);
#pragma unroll
    for (int i = 0; i < 2; ++i)
      gld16(w3b + sB1[i] + k0, base + 16384 + ldsO[i]);
  };

  // prologue: tiles 0,1 -> bufs 0,1; publish tile 0 (keep tile 1 in flight)
  stage(0, 0);
  stage(1, 1);
  asm volatile("s_waitcnt vmcnt(6)" ::: "memory");
  __builtin_amdgcn_sched_barrier(0);
  __builtin_amdgcn_s_barrier();
  __builtin_amdgcn_sched_barrier(0);

  int bR = 0, bS = 2;                          // read buf, stage buf
#pragma unroll 3
  for (int kt = 0; kt < NT; ++kt) {
    const int t2 = (kt + 2 < NT) ? kt + 2 : NT - 1;   // clamp: uniform counts
    stage(t2, bS);
    char* base = lds + bR * 24576;
    s16x8 af[4], b1f[4], b3f[4];
#pragma unroll
    for (int mi = 0; mi < 4; ++mi)
      af[mi] = *(const s16x8*)(base + aoff + mi * 1024);
#pragma unroll
    for (int ni = 0; ni < 4; ++ni) {
      b1f[ni] = *(const s16x8*)(base + 8192 + boff + ni * 1024);
      b3f[ni] = *(const s16x8*)(base + 16384 + boff + ni * 1024);
    }
#pragma unroll
    for (int mi = 0; mi < 4; ++mi)
#pragma unroll
      for (int ni = 0; ni < 4; ++ni) {
        accG[mi][ni] = __builtin_amdgcn_mfma_f32_16x16x32_bf16(
            af[mi], b1f[ni], accG[mi][ni], 0, 0, 0);
        accU[mi][ni] = __builtin_amdgcn_mfma_f32_16x16x32_bf16(
            af[mi], b3f[ni], accU[mi][ni], 0, 0, 0);
      }
    asm volatile("s_waitcnt vmcnt(6)" ::: "memory");   // tile kt+1 published
    __builtin_amdgcn_sched_barrier(0);
    __builtin_amdgcn_s_barrier();
    __builtin_amdgcn_sched_barrier(0);
    bR = (bR == 2) ? 0 : bR + 1;
    bS = (bS == 2) ? 0 : bS + 1;
  }

  const int erow = (lane >> 4) * 4;
  const int ecol = lane & 15;
#pragma unroll
  for (int mi = 0; mi < 4; ++mi)
#pragma unroll
    for (int ni = 0; ni < 4; ++ni) {
      const size_t cb = ncol0 + wc * 64 + ni * 16 + ecol;
#pragma unroll
      for (int j = 0; j < 4; ++j) {
        const size_t r = hrow0 + wr * 64 + mi * 16 + erow + j;
        const float g = accG[mi][ni][j];
        const float uu = accU[mi][ni][j];
        const float h = g / (1.f + __expf(-g)) * uu;
        hb[r * FDIM + cb] = __float2bfloat16(h);
      }
    }
}

// ============================================================================
// Fused down grouped GEMM — ROUND-12 EXACT (386 us, MfmaUtil 31.4%).
// 3-stage pipeline + counted vmcnt(6); two w2 panels share staged h tile;
// grid x=expert -> XCD ownership; atomicAdd epilogue (deterministic).
// ============================================================================
__global__ __launch_bounds__(256, 2) void moe_down_k(
    const __hip_bfloat16* __restrict__ hb, const __hip_bfloat16* __restrict__ w2b,
    float* __restrict__ out, const int* __restrict__ cnt,
    const int* __restrict__ ebase, const int* __restrict__ elist,
    const float* __restrict__ ewts) {
  constexpr int NT = FDIM / 32;              // 128 K-steps
  const int e = blockIdx.x;                  // expert on XCD e
  const int count = cnt[e];
  const int mt = blockIdx.y;
  if (mt * 128 >= count) return;
  const int bn0 = blockIdx.z * 256;          // D col base (two 128-panels)

  __shared__ char lds[73728];                // 3 bufs x (A 8K | B0 8K | B1 8K)
  const int t = threadIdx.x;
  const int lane = t & 63, wv = t >> 6;
  const int wr = wv >> 1, wc = wv & 1;
  const int* lst = elist + e * N_TOK;
  const size_t hrow0 = (size_t)ebase[e] + (size_t)mt * 128;

  const int r0 = t >> 2;
  const int ks = (t & 3) ^ ((r0 >> 1) & 3);
  size_t sA[2], sB[2];
  int ldsO[2];
#pragma unroll
  for (int i = 0; i < 2; ++i) {
    const int r = r0 + i * 64;
    sA[i] = (hrow0 + r) * (size_t)FDIM + ks * 8;
    sB[i] = ((size_t)e * 2048 + bn0 + r) * (size_t)FDIM + ks * 8;  // panel0 rows
    ldsO[i] = i * 4096 + wv * 1024;
  }
  const size_t sBp = 128 * (size_t)FDIM;     // +128 rows -> panel1

  const int fr = lane & 15;
  const int swzc = ((lane >> 4) ^ ((fr >> 1) & 3)) << 4;
  const int aoff = (wr * 64 + fr) * 64 + swzc;
  const int boff = (wc * 64 + fr) * 64 + swzc;

  f32x4 accP[2][4][4];
#pragma unroll
  for (int p = 0; p < 2; ++p)
#pragma unroll
    for (int mi = 0; mi < 4; ++mi)
#pragma unroll
      for (int ni = 0; ni < 4; ++ni) accP[p][mi][ni] = {0.f, 0.f, 0.f, 0.f};

  auto stage = [&](int kt, int b) {          // 6 gld16, always
    const int k0 = kt * 32;
    char* base = lds + b * 24576;
#pragma unroll
    for (int i = 0; i < 2; ++i)
      gld16(hb + sA[i] + k0, base + ldsO[i]);
#pragma unroll
    for (int i = 0; i < 2; ++i)
      gld16(w2b + sB[i] + k0, base + 8192 + ldsO[i]);
#pragma unroll
    for (int i = 0; i < 2; ++i)
      gld16(w2b + sB[i] + sBp + k0, base + 16384 + ldsO[i]);
  };

  stage(0, 0);
  stage(1, 1);
  asm volatile("s_waitcnt vmcnt(6)" ::: "memory");
  __builtin_amdgcn_sched_barrier(0);
  __builtin_amdgcn_s_barrier();
  __builtin_amdgcn_sched_barrier(0);

  int bR = 0, bS = 2;                        // read buf, stage buf
#pragma unroll 3
  for (int kt = 0; kt < NT; ++kt) {
    const int t2 = (kt + 2 < NT) ? kt + 2 : NT - 1;   // clamp: uniform counts
    stage(t2, bS);
    char* base = lds + bR * 24576;
    s16x8 af[4], b0f[4], b1f[4];
#pragma unroll
    for (int mi = 0; mi < 4; ++mi)
      af[mi] = *(const s16x8*)(base + aoff + mi * 1024);
#pragma unroll
    for (int ni = 0; ni < 4; ++ni) {
      b0f[ni] = *(const s16x8*)(base + 8192 + boff + ni * 1024);
      b1f[ni] = *(const s16x8*)(base + 16384 + boff + ni * 1024);
    }
#pragma unroll
    for (int mi = 0; mi < 4; ++mi)
#pragma unroll
      for (int ni = 0; ni < 4; ++ni) {
        accP[0][mi][ni] = __builtin_amdgcn_mfma_f32_16x16x32_bf16(
            af[mi], b0f[ni], accP[0][mi][ni], 0, 0, 0);
        accP[1][mi][ni] = __builtin_amdgcn_mfma_f32_16x16x32_bf16(
            af[mi], b1f[ni], accP[1][mi][ni], 0, 0, 0);
      }
    asm volatile("s_waitcnt vmcnt(6)" ::: "memory");   // tile kt+1 published
    __builtin_amdgcn_sched_barrier(0);
    __builtin_amdgcn_s_barrier();
    __builtin_amdgcn_sched_barrier(0);
    bR = (bR == 2) ? 0 : bR + 1;
    bS = (bS == 2) ? 0 : bS + 1;
  }

  const int erow = (lane >> 4) * 4;
  const int ecol = lane & 15;
#pragma unroll
  for (int mi = 0; mi < 4; ++mi)
#pragma unroll
    for (int j = 0; j < 4; ++j) {
      const int i = mt * 128 + wr * 64 + mi * 16 + erow + j;
      if (i < count) {
        const uint32_t info = (uint32_t)lst[i];
        const int tok = (int)(info & 0x7fffffffu);
        const float wt = ewts[e * N_TOK + i];
        float* prow = out + (size_t)tok * DIM;
#pragma unroll
        for (int p = 0; p < 2; ++p)
#pragma unroll
          for (int ni = 0; ni < 4; ++ni) {
            const int cb = bn0 + p * 128 + wc * 64 + ni * 16 + ecol;
            atomicAdd(prow + cb, wt * accP[p][mi][ni][j]);
          }
      }
    }
}

extern "C" void kernel_launch(void* const* d_in, const int* in_sizes, int n_in,
                              void* d_out, int out_size, void* d_ws, size_t ws_size,
                              hipStream_t stream) {
  const float* stm = (const float*)d_in[0];
  const float* gw = (const float*)d_in[1];
  const float* w1 = (const float*)d_in[2];
  const float* w2 = (const float*)d_in[3];
  const float* w3 = (const float*)d_in[4];
  float* out = (float*)d_out;
  char* ws = (char*)d_ws;

  __hip_bfloat16* xb = (__hip_bfloat16*)(ws + XB_OFF);
  __hip_bfloat16* hb = (__hip_bfloat16*)(ws + HB_OFF);
  __hip_bfloat16* wb1 = (__hip_bfloat16*)(ws + WB1_OFF);
  __hip_bfloat16* wb3 = (__hip_bfloat16*)(ws + WB3_OFF);
  __hip_bfloat16* w2full = (__hip_bfloat16*)(ws + WB1_OFF);  // 134MB spans wb1+wb3
  int* cnt = (int*)(ws + CNT_OFF);
  int* ebase = (int*)(ws + EBASE_OFF);
  int* elist = (int*)(ws + ELIST_OFF);
  float* ewts = (float*)(ws + EWTS_OFF);

  init_k<<<1, 64, 0, stream>>>(cnt);
  router_k<<<N_TOK, 256, 0, stream>>>(stm, gw, xb, cnt, elist, ewts);
  scan_k<<<1, 64, 0, stream>>>(cnt, ebase);
  zero_out_k<<<N_TOK * DIM / 1024, 256, 0, stream>>>(out);

  const dim3 gUp(16, 64, 8);   // (N-panels/half, M-tiles, experts)
  const dim3 gDn(8, 64, 8);    // (experts, M-tiles, 256-col D panels)

  // fused gate+up, F-half 0
  convW_k<<<2048, 256, 0, stream>>>(w1, wb1, 0, 2048, FDIM, DIM);
  convW_k<<<2048, 256, 0, stream>>>(w3, wb3, 0, 2048, FDIM, DIM);
  moe_up_k<<<gUp, 256, 0, stream>>>(xb, wb1, wb3, hb, cnt, ebase, elist, 0);
  // fused gate+up, F-half 1
  convW_k<<<2048, 256, 0, stream>>>(w1, wb1, 2048, 2048, FDIM, DIM);
  convW_k<<<2048, 256, 0, stream>>>(w3, wb3, 2048, 2048, FDIM, DIM);
  moe_up_k<<<gUp, 256, 0, stream>>>(xb, wb1, wb3, hb, cnt, ebase, elist, 2048);

  // down: full w2 -> bf16 (wb1+wb3 region, both dead), then one fused launch
  convW_k<<<4096, 256, 0, stream>>>(w2, w2full, 0, 2048, DIM, FDIM);
  moe_down_k<<<gDn, 256, 0, stream>>>(hb, w2full, out, cnt, ebase, elist, ewts);
}